// Round 10
// baseline (249.909 us; speedup 1.0000x reference)
//
#include <hip/hip_runtime.h>
#include <hip/hip_bf16.h>

#define BN 4
#define CN 320
#define NN 4096
#define EN 2
#define DKN 32
#define DVN 160

typedef __bf16 bf16;
typedef __bf16 bf16x8 __attribute__((ext_vector_type(8)));
typedef float f32x4 __attribute__((ext_vector_type(4)));

static __device__ __forceinline__ f32x4 mfma16(bf16x8 a, bf16x8 b, f32x4 c) {
  return __builtin_amdgcn_mfma_f32_16x16x32_bf16(a, b, c, 0, 0, 0);
}

// V cell order (unchanged from R9):
//   Vc[(((be*128+T)*10+vt)*4+g)*128 + lr*8 + (h*4+i)] = V[dv=vt*16+lr][key=32T+16h+4g+i]
//   -> per 32-key tile T: 10KB contiguous; lane l reads its PV B-fragment as one bf16x8 at l*16B.
// K cell order (new): Kc[(be*128+T)*1024 + frag*512 + (o*16 + (k&15))*8 + j]
//   = K[dk=8o+j][key 32T + frag*16 + (k&15)] -> per tile: 2KB contiguous, lane-linear A-fragments.

// ---------------- kernel 1: cast/concat weights ----------------
__global__ __launch_bounds__(256) void k_prep(
    const float* __restrict__ Wq, const float* __restrict__ bq,
    const float* __restrict__ Wk, const float* __restrict__ bk,
    const float* __restrict__ Wv, const float* __restrict__ bv,
    const float* __restrict__ Wm,
    bf16* __restrict__ W_all, bf16* __restrict__ Wm_bf, float* __restrict__ b_all) {
  int t = blockIdx.x * 256 + threadIdx.x;
  if (t < 448 * CN) {
    int r = t / CN;
    float v;
    if (r < 64) v = Wq[t];
    else if (r < 128) v = Wk[t - 64 * CN];
    else v = Wv[t - 128 * CN];
    W_all[t] = (bf16)v;
  }
  if (t < 320 * 320) Wm_bf[t] = (bf16)Wm[t];
  if (t < 448) {
    float v;
    if (t < 64) v = bq[t];
    else if (t < 128) v = bk[t - 64];
    else v = bv[t - 128];
    b_all[t] = v;
  }
}

// ---------------- kernel 2: x [b][c][n] f32 -> xT [b][n][c] bf16 ----------------
__global__ __launch_bounds__(256) void k_xt(const float* __restrict__ x, bf16* __restrict__ xT) {
  int blk = blockIdx.x;
  int b = blk / 640;
  int rem = blk - b * 640;
  int cc = rem >> 4;
  int nb = rem & 15;
  int n = nb * 256 + threadIdx.x;
  const float* xp = x + ((size_t)b * CN + cc * 8) * NN + n;
  bf16x8 v;
#pragma unroll
  for (int j = 0; j < 8; j++) v[j] = (bf16)xp[(size_t)j * NN];
  *(bf16x8*)(xT + ((size_t)b * NN + n) * CN + cc * 8) = v;
}

// ---------------- kernel 3: projection GEMM ----------------
__global__ __launch_bounds__(256) void k_proj(
    const bf16* __restrict__ W_all, const float* __restrict__ b_all,
    const bf16* __restrict__ xT, float* __restrict__ QK, bf16* __restrict__ Vc) {
  int blk = blockIdx.x;
  int b = blk / 448;
  int rem = blk - b * 448;
  int mt = rem >> 4, nb = rem & 15;
  int w = threadIdx.x >> 6, l = threadIdx.x & 63;
  int lg = l >> 4, lr = l & 15;
  int m0 = mt * 16;
  int n0 = nb * 256 + w * 64;
  f32x4 acc[4] = {};
  const bf16* wp = W_all + (m0 + lr) * CN + 8 * lg;
  const bf16* xp = xT + ((size_t)b * NN + n0 + lr) * CN + 8 * lg;
#pragma unroll 2
  for (int c0 = 0; c0 < CN; c0 += 32) {
    bf16x8 a = *(const bf16x8*)(wp + c0);
#pragma unroll
    for (int j = 0; j < 4; j++) {
      bf16x8 bb = *(const bf16x8*)(xp + j * 16 * CN + c0);
      acc[j] = mfma16(a, bb, acc[j]);
    }
  }
#pragma unroll
  for (int i = 0; i < 4; i++) {
    int row = m0 + 4 * lg + i;
    float bias = b_all[row];
    if (row < 128) {
      float* qk = QK + ((size_t)b * 128 + row) * NN + n0 + lr;
#pragma unroll
      for (int j = 0; j < 4; j++) qk[j * 16] = acc[j][i] + bias;
    } else {
      int rr = row - 128;
      int e = rr / 160, dvl = rr - e * 160;
      int vt = dvl >> 4, lrc = dvl & 15;
      size_t beI = (size_t)(b * 2 + e);
#pragma unroll
      for (int j = 0; j < 4; j++) {
        int key = n0 + j * 16 + lr;
        int T = key >> 5, h = (key >> 4) & 1, g = (key >> 2) & 3, ic = key & 3;
        Vc[(((beI * 128 + T) * 10 + vt) * 4 + g) * 128 + lrc * 8 + h * 4 + ic] =
            (bf16)(acc[j][i] + bias);
      }
    }
  }
}

// ---------------- kernel 4: L2 normalize Q,K; Q -> [be][n][32], K -> cell order Kc ----------------
__global__ __launch_bounds__(256) void k_norm(
    const float* __restrict__ QK, bf16* __restrict__ Qn, bf16* __restrict__ Kc) {
  int t = blockIdx.x * 256 + threadIdx.x;
  int isk = t >> 15;
  int r = t & 32767;
  int b = r >> 13, e = (r >> 12) & 1, n = r & (NN - 1);
  const float* p = QK + ((size_t)b * 128 + isk * 64 + e * 32) * NN + n;
  float v[32];
  float ss = 0.f;
#pragma unroll
  for (int d = 0; d < 32; d++) { float q = p[(size_t)d * NN]; v[d] = q; ss += q * q; }
  float s = 1.0f / fmaxf(sqrtf(ss), 1e-6f);
  if (!isk) {
    bf16* o = Qn + ((size_t)(b * 2 + e) * NN + n) * 32;
#pragma unroll
    for (int d0 = 0; d0 < 32; d0 += 8) {
      bf16x8 vo;
#pragma unroll
      for (int j = 0; j < 8; j++) vo[j] = (bf16)(v[d0 + j] * s);
      *(bf16x8*)(o + d0) = vo;
    }
  } else {
    // cell order: frag = (n>>4)&1, lane = o*16 + (n&15), elems = dk octet o
    bf16* kc = Kc + ((size_t)(b * 2 + e) * 128 + (n >> 5)) * 1024 + ((n >> 4) & 1) * 512 +
               (n & 15) * 8;
#pragma unroll
    for (int o = 0; o < 4; o++) {
      bf16x8 vo;
#pragma unroll
      for (int j = 0; j < 8; j++) vo[j] = (bf16)(v[o * 8 + j] * s);
      *(bf16x8*)(kc + o * 128) = vo;
    }
  }
}

// ---------------- kernel 5: attention ----------------
// 512 blocks = be*64 q-blocks; 4 waves x 16 queries each, all keys per wave.
// K+V tile (12KB, lane-linear cell order) double-buffered in LDS via global_load_lds;
// all 4 waves share the stream -> 2x less L2 traffic than R9, conflict-free ds_reads.
__global__ __launch_bounds__(256) void k_attn(
    const bf16* __restrict__ Qn, const bf16* __restrict__ Kc,
    const bf16* __restrict__ Vc, bf16* __restrict__ Rt) {
  __shared__ __align__(16) char smem[2][12288];   // [K 2KB | V 10KB] per buffer
  int blk = blockIdx.x;            // be*64 + qblk
  int be = blk >> 6, qblk = blk & 63;
  int w = threadIdx.x >> 6, l = threadIdx.x & 63;
  int lg = l >> 4, lr = l & 15;
  int qb = qblk * 64 + w * 16;
  bf16x8 qf = *(const bf16x8*)(Qn + ((size_t)be * NN + qb + lr) * 32 + 8 * lg);
  const char* kbase = (const char*)Kc + (size_t)be * 128 * 2048;
  const char* vbase = (const char*)Vc + (size_t)be * 128 * 10240;
  int ch = w * 3;                  // this wave's 3 chunks of the 12KB tile
  f32x4 acc[10] = {};
  float rs = 0.f;
  // prologue: stage tile 0 into buf 0
#pragma unroll
  for (int c = 0; c < 3; c++) {
    int chunk = ch + c;
    const char* src = (chunk < 2) ? (kbase + chunk * 1024 + l * 16)
                                  : (vbase + (chunk - 2) * 1024 + l * 16);
    __builtin_amdgcn_global_load_lds(
        (const __attribute__((address_space(1))) void*)src,
        (__attribute__((address_space(3))) void*)(&smem[0][chunk * 1024 + l * 16]), 16, 0, 0);
  }
  __syncthreads();
  for (int T = 0; T < 128; T++) {
    int cur = T & 1;
    if (T + 1 < 128) {
      const char* kt = kbase + (size_t)(T + 1) * 2048;
      const char* vt_ = vbase + (size_t)(T + 1) * 10240;
#pragma unroll
      for (int c = 0; c < 3; c++) {
        int chunk = ch + c;
        const char* src = (chunk < 2) ? (kt + chunk * 1024 + l * 16)
                                      : (vt_ + (chunk - 2) * 1024 + l * 16);
        __builtin_amdgcn_global_load_lds(
            (const __attribute__((address_space(1))) void*)src,
            (__attribute__((address_space(3))) void*)(&smem[cur ^ 1][chunk * 1024 + l * 16]),
            16, 0, 0);
      }
    }
    const bf16* Kl = (const bf16*)(&smem[cur][0]);
    const bf16* Vl = (const bf16*)(&smem[cur][2048]);
    bf16x8 kf0 = *(const bf16x8*)(Kl + l * 8);
    bf16x8 kf1 = *(const bf16x8*)(Kl + 512 + l * 8);
    f32x4 zero = {};
    f32x4 s0 = mfma16(kf0, qf, zero);   // S^T[key 0-15][q]
    f32x4 s1 = mfma16(kf1, qf, zero);   // S^T[key 16-31][q]
    bf16x8 pf;
#pragma unroll
    for (int i = 0; i < 4; i++) {
      float e0 = __expf(s0[i]), e1 = __expf(s1[i]);
      rs += e0 + e1;
      pf[i] = (bf16)e0; pf[4 + i] = (bf16)e1;
    }
#pragma unroll
    for (int vt = 0; vt < 10; vt++) {
      bf16x8 vf = *(const bf16x8*)(Vl + vt * 512 + l * 8);
      acc[vt] = mfma16(pf, vf, acc[vt]);
    }
    __syncthreads();   // drains vmcnt (next buf staged) + orders buffer reuse
  }
  // rowsum over lane-groups: all of query lr's partials live at lanes with same (l&15)
  rs += __shfl_xor(rs, 16);
  rs += __shfl_xor(rs, 32);
  f32x4 rinv;
#pragma unroll
  for (int i = 0; i < 4; i++) rinv[i] = 1.0f / __shfl(rs, 4 * lg + i);
  int b = be >> 1, e = be & 1;
#pragma unroll
  for (int vt = 0; vt < 10; vt++)
#pragma unroll
    for (int i = 0; i < 4; i++) {
      int q = qb + 4 * lg + i;
      Rt[((size_t)b * NN + q) * 320 + e * 160 + vt * 16 + lr] = (bf16)(acc[vt][i] * rinv[i]);
    }
}

// ---------------- kernel 6: merge GEMM + bias + residual ----------------
__global__ __launch_bounds__(256) void k_merge(
    const bf16* __restrict__ Wm_bf, const float* __restrict__ bm,
    const bf16* __restrict__ Rt, const float* __restrict__ x, float* __restrict__ out) {
  int blk = blockIdx.x;
  int b = blk / 320;
  int rem = blk - b * 320;
  int ct = rem >> 4, nb = rem & 15;
  int w = threadIdx.x >> 6, l = threadIdx.x & 63;
  int lg = l >> 4, lr = l & 15;
  int c0 = ct * 16, n0 = nb * 256 + w * 64;
  f32x4 acc[4] = {};
  const bf16* ap = Wm_bf + (c0 + lr) * 320 + 8 * lg;
  const bf16* bp = Rt + ((size_t)b * NN + n0 + lr) * 320 + 8 * lg;
#pragma unroll 2
  for (int f0 = 0; f0 < 320; f0 += 32) {
    bf16x8 a = *(const bf16x8*)(ap + f0);
#pragma unroll
    for (int j = 0; j < 4; j++) {
      bf16x8 bb = *(const bf16x8*)(bp + j * 16 * 320 + f0);
      acc[j] = mfma16(a, bb, acc[j]);
    }
  }
#pragma unroll
  for (int i = 0; i < 4; i++) {
    int c = c0 + 4 * lg + i;
    float bias = bm[c];
    const float* xp = x + ((size_t)b * 320 + c) * NN + n0 + lr;
    float* op = out + ((size_t)b * 320 + c) * NN + n0 + lr;
#pragma unroll
    for (int j = 0; j < 4; j++) op[j * 16] = acc[j][i] + bias + xp[j * 16];
  }
}

extern "C" void kernel_launch(void* const* d_in, const int* in_sizes, int n_in,
                              void* d_out, int out_size, void* d_ws, size_t ws_size,
                              hipStream_t stream) {
  const float* x  = (const float*)d_in[0];
  const float* Wq = (const float*)d_in[1];
  const float* bq = (const float*)d_in[2];
  const float* Wk = (const float*)d_in[3];
  const float* bk = (const float*)d_in[4];
  const float* Wv = (const float*)d_in[5];
  const float* bv = (const float*)d_in[6];
  const float* Wm = (const float*)d_in[7];
  const float* bm = (const float*)d_in[8];
  float* out = (float*)d_out;
  char* ws = (char*)d_ws;
  // workspace layout (bytes, 256-aligned)
  bf16*  W_all = (bf16*)(ws + 0);           //  448*320*2      = 286720
  bf16*  Wm_bf = (bf16*)(ws + 286720);      //  320*320*2      = 204800 -> 491520
  float* b_all = (float*)(ws + 491520);     //  448*4          -> pad 493568
  bf16*  xT    = (bf16*)(ws + 493568);      //  4*4096*320*2   = 10485760 -> 10979328
  float* QK    = (float*)(ws + 10979328);   //  4*128*4096*4   = 8388608  -> 19367936
  bf16*  Qn    = (bf16*)(ws + 19367936);    //  8*4096*32*2    = 2097152  -> 21465088
  bf16*  Kc    = (bf16*)(ws + 21465088);    //  8*128*1024*2   = 2097152  -> 23562240
  bf16*  Vc    = (bf16*)(ws + 23562240);    //  8*128*5120*2   = 10485760 -> 34048000
  bf16*  Rt    = (bf16*)(ws + 34048000);    //  4*4096*320*2   = 10485760 -> 44533760

  k_prep<<<560, 256, 0, stream>>>(Wq, bq, Wk, bk, Wv, bv, Wm, W_all, Wm_bf, b_all);
  k_xt<<<2560, 256, 0, stream>>>(x, xT);
  k_proj<<<1792, 256, 0, stream>>>(W_all, b_all, xT, QK, Vc);
  k_norm<<<256, 256, 0, stream>>>(QK, Qn, Kc);
  k_attn<<<512, 256, 0, stream>>>(Qn, Kc, Vc, Rt);
  k_merge<<<1280, 256, 0, stream>>>(Wm_bf, bm, Rt, x, out);
}

// Round 11
// 236.353 us; speedup vs baseline: 1.0574x; 1.0574x over previous
//
#include <hip/hip_runtime.h>
#include <hip/hip_bf16.h>

#define BN 4
#define CN 320
#define NN 4096
#define EN 2
#define DKN 32
#define DVN 160

typedef __bf16 bf16;
typedef __bf16 bf16x8 __attribute__((ext_vector_type(8)));
typedef float f32x4 __attribute__((ext_vector_type(4)));

static __device__ __forceinline__ f32x4 mfma16(bf16x8 a, bf16x8 b, f32x4 c) {
  return __builtin_amdgcn_mfma_f32_16x16x32_bf16(a, b, c, 0, 0, 0);
}

// V cell order:
//   Vc[(((be*128+T)*10+vt)*4+g)*128 + lr*8 + (h*4+i)] = V[dv=vt*16+lr][key=32T+16h+4g+i]
//   -> lane l reads its PV B-fragment as ONE contiguous bf16x8 (1KB/wave load).
// K stays row-per-key [be][n][32]: lane l=lg*16+lr reads 16B at (key)*64B + lg*16 ->
//   4 lg-lanes cover each 64B line fully (line-efficient).

// ---------------- kernel 1: cast/concat weights ----------------
__global__ __launch_bounds__(256) void k_prep(
    const float* __restrict__ Wq, const float* __restrict__ bq,
    const float* __restrict__ Wk, const float* __restrict__ bk,
    const float* __restrict__ Wv, const float* __restrict__ bv,
    const float* __restrict__ Wm,
    bf16* __restrict__ W_all, bf16* __restrict__ Wm_bf, float* __restrict__ b_all) {
  int t = blockIdx.x * 256 + threadIdx.x;
  if (t < 448 * CN) {
    int r = t / CN;
    float v;
    if (r < 64) v = Wq[t];
    else if (r < 128) v = Wk[t - 64 * CN];
    else v = Wv[t - 128 * CN];
    W_all[t] = (bf16)v;
  }
  if (t < 320 * 320) Wm_bf[t] = (bf16)Wm[t];
  if (t < 448) {
    float v;
    if (t < 64) v = bq[t];
    else if (t < 128) v = bk[t - 64];
    else v = bv[t - 128];
    b_all[t] = v;
  }
}

// ---------------- kernel 2: x [b][c][n] f32 -> xT [b][n][c] bf16 ----------------
__global__ __launch_bounds__(256) void k_xt(const float* __restrict__ x, bf16* __restrict__ xT) {
  int blk = blockIdx.x;
  int b = blk / 640;
  int rem = blk - b * 640;
  int cc = rem >> 4;
  int nb = rem & 15;
  int n = nb * 256 + threadIdx.x;
  const float* xp = x + ((size_t)b * CN + cc * 8) * NN + n;
  bf16x8 v;
#pragma unroll
  for (int j = 0; j < 8; j++) v[j] = (bf16)xp[(size_t)j * NN];
  *(bf16x8*)(xT + ((size_t)b * NN + n) * CN + cc * 8) = v;
}

// ---------------- kernel 3: projection GEMM ----------------
__global__ __launch_bounds__(256) void k_proj(
    const bf16* __restrict__ W_all, const float* __restrict__ b_all,
    const bf16* __restrict__ xT, float* __restrict__ QK, bf16* __restrict__ Vc) {
  int blk = blockIdx.x;
  int b = blk / 448;
  int rem = blk - b * 448;
  int mt = rem >> 4, nb = rem & 15;
  int w = threadIdx.x >> 6, l = threadIdx.x & 63;
  int lg = l >> 4, lr = l & 15;
  int m0 = mt * 16;
  int n0 = nb * 256 + w * 64;
  f32x4 acc[4] = {};
  const bf16* wp = W_all + (m0 + lr) * CN + 8 * lg;
  const bf16* xp = xT + ((size_t)b * NN + n0 + lr) * CN + 8 * lg;
#pragma unroll 2
  for (int c0 = 0; c0 < CN; c0 += 32) {
    bf16x8 a = *(const bf16x8*)(wp + c0);
#pragma unroll
    for (int j = 0; j < 4; j++) {
      bf16x8 bb = *(const bf16x8*)(xp + j * 16 * CN + c0);
      acc[j] = mfma16(a, bb, acc[j]);
    }
  }
#pragma unroll
  for (int i = 0; i < 4; i++) {
    int row = m0 + 4 * lg + i;
    float bias = b_all[row];
    if (row < 128) {
      float* qk = QK + ((size_t)b * 128 + row) * NN + n0 + lr;
#pragma unroll
      for (int j = 0; j < 4; j++) qk[j * 16] = acc[j][i] + bias;
    } else {
      int rr = row - 128;
      int e = rr / 160, dvl = rr - e * 160;
      int vt = dvl >> 4, lrc = dvl & 15;
      size_t beI = (size_t)(b * 2 + e);
#pragma unroll
      for (int j = 0; j < 4; j++) {
        int key = n0 + j * 16 + lr;
        int T = key >> 5, h = (key >> 4) & 1, g = (key >> 2) & 3, ic = key & 3;
        Vc[(((beI * 128 + T) * 10 + vt) * 4 + g) * 128 + lrc * 8 + h * 4 + ic] =
            (bf16)(acc[j][i] + bias);
      }
    }
  }
}

// ---------------- kernel 4: L2 normalize Q,K over dk; write [be][n][32] bf16 ----------------
__global__ __launch_bounds__(256) void k_norm(
    const float* __restrict__ QK, bf16* __restrict__ Qn, bf16* __restrict__ Kn) {
  int t = blockIdx.x * 256 + threadIdx.x;
  int isk = t >> 15;
  int r = t & 32767;
  int b = r >> 13, e = (r >> 12) & 1, n = r & (NN - 1);
  const float* p = QK + ((size_t)b * 128 + isk * 64 + e * 32) * NN + n;
  float v[32];
  float ss = 0.f;
#pragma unroll
  for (int d = 0; d < 32; d++) { float q = p[(size_t)d * NN]; v[d] = q; ss += q * q; }
  float s = 1.0f / fmaxf(sqrtf(ss), 1e-6f);
  bf16* o = (isk ? Kn : Qn) + ((size_t)(b * 2 + e) * NN + n) * 32;
#pragma unroll
  for (int d0 = 0; d0 < 32; d0 += 8) {
    bf16x8 vo;
#pragma unroll
    for (int j = 0; j < 8; j++) vo[j] = (bf16)(v[d0 + j] * s);
    *(bf16x8*)(o + d0) = vo;
  }
}

// ---------------- kernel 5: attention ----------------
// Block = (be, 32 queries), 4 waves each on a disjoint key-quarter (split-K flash).
// be = blockIdx % 8 -> round-robin dispatch pins each be to ONE XCD, so that XCD's
// L2 holds exactly that be's K+V (3.3MB <= 4MB): V re-reads become L2 hits.
__global__ __launch_bounds__(256) void k_attn(
    const bf16* __restrict__ Qn, const bf16* __restrict__ Kn,
    const bf16* __restrict__ Vc, bf16* __restrict__ Rt) {
  __shared__ float sbuf[64][83];   // stride 83: 2-way bank alias only (free)
  int blk = blockIdx.x;            // qc*8 + be  (be == XCD id under %8 round-robin)
  int be = blk & 7, qc = blk >> 3;
  int w = threadIdx.x >> 6, l = threadIdx.x & 63;
  int lg = l >> 4, lr = l & 15;
  int qb = qc * 32;
  const bf16* qbase = Qn + ((size_t)be * NN + qb) * 32 + 8 * lg;
  bf16x8 qf0 = *(const bf16x8*)(qbase + lr * 32);
  bf16x8 qf1 = *(const bf16x8*)(qbase + (16 + lr) * 32);
  const bf16* kbase = Kn + (size_t)be * NN * 32 + 8 * lg;
  const bf16* vbase = Vc + (size_t)be * (128 * 10 * 512) + (size_t)l * 8;
  int mstart = w * (NN / 4), mend = mstart + (NN / 4);
  f32x4 acc0[10] = {};
  f32x4 acc1[10] = {};
  float rs0 = 0.f, rs1 = 0.f;
  bf16x8 kf0 = *(const bf16x8*)(kbase + (size_t)(mstart + lr) * 32);
  bf16x8 kf1 = *(const bf16x8*)(kbase + (size_t)(mstart + 16 + lr) * 32);
  for (int m0 = mstart; m0 < mend; m0 += 32) {
    // V fragments for this 32-key tile: 10 contiguous 16B/lane loads
    const bf16* vp = vbase + (size_t)(m0 >> 5) * (10 * 512);
    bf16x8 vf[10];
#pragma unroll
    for (int vt = 0; vt < 10; vt++) vf[vt] = *(const bf16x8*)(vp + vt * 512);
    f32x4 zero = {};
    f32x4 s00 = mfma16(kf0, qf0, zero);  // S^T[m][q], m-half 0, q-subtile 0
    f32x4 s01 = mfma16(kf1, qf0, zero);
    f32x4 s10 = mfma16(kf0, qf1, zero);
    f32x4 s11 = mfma16(kf1, qf1, zero);
    // prefetch next K fragments
    if (m0 + 32 < mend) {
      kf0 = *(const bf16x8*)(kbase + (size_t)(m0 + 32 + lr) * 32);
      kf1 = *(const bf16x8*)(kbase + (size_t)(m0 + 48 + lr) * 32);
    }
    bf16x8 pf0, pf1;
#pragma unroll
    for (int i = 0; i < 4; i++) {
      float e00 = __expf(s00[i]), e01 = __expf(s01[i]);
      float e10 = __expf(s10[i]), e11 = __expf(s11[i]);
      rs0 += e00 + e01;
      rs1 += e10 + e11;
      pf0[i] = (bf16)e00; pf0[4 + i] = (bf16)e01;
      pf1[i] = (bf16)e10; pf1[4 + i] = (bf16)e11;
    }
    __builtin_amdgcn_s_setprio(1);
#pragma unroll
    for (int vt = 0; vt < 10; vt++) {
      acc0[vt] = mfma16(pf0, vf[vt], acc0[vt]);
      acc1[vt] = mfma16(pf1, vf[vt], acc1[vt]);
    }
    __builtin_amdgcn_s_setprio(0);
  }
  // cross-wave reduction of partial numerators + rowsums into wave 0
  for (int r = 1; r < 4; ++r) {
    if (w == r) {
      float* p = &sbuf[l][0];
#pragma unroll
      for (int vt = 0; vt < 10; vt++)
#pragma unroll
        for (int i = 0; i < 4; i++) {
          p[vt * 4 + i] = acc0[vt][i];
          p[40 + vt * 4 + i] = acc1[vt][i];
        }
      p[80] = rs0; p[81] = rs1;
    }
    __syncthreads();
    if (w == 0) {
      const float* p = &sbuf[l][0];
#pragma unroll
      for (int vt = 0; vt < 10; vt++)
#pragma unroll
        for (int i = 0; i < 4; i++) {
          acc0[vt][i] += p[vt * 4 + i];
          acc1[vt][i] += p[40 + vt * 4 + i];
        }
      rs0 += p[80]; rs1 += p[81];
    }
    __syncthreads();
  }
  if (w == 0) {
    // complete the rowsums across the 4 lane-groups, then broadcast in-wave
    rs0 += __shfl_xor(rs0, 16); rs0 += __shfl_xor(rs0, 32);
    rs1 += __shfl_xor(rs1, 16); rs1 += __shfl_xor(rs1, 32);
    f32x4 rinv0, rinv1;
#pragma unroll
    for (int i = 0; i < 4; i++) {
      rinv0[i] = 1.0f / __shfl(rs0, 4 * lg + i);
      rinv1[i] = 1.0f / __shfl(rs1, 4 * lg + i);
    }
    int b = be >> 1, e = be & 1;
#pragma unroll
    for (int vt = 0; vt < 10; vt++) {
#pragma unroll
      for (int i = 0; i < 4; i++) {
        int q0 = qb + 4 * lg + i;
        int q1 = qb + 16 + 4 * lg + i;
        Rt[((size_t)b * NN + q0) * 320 + e * 160 + vt * 16 + lr] = (bf16)(acc0[vt][i] * rinv0[i]);
        Rt[((size_t)b * NN + q1) * 320 + e * 160 + vt * 16 + lr] = (bf16)(acc1[vt][i] * rinv1[i]);
      }
    }
  }
}

// ---------------- kernel 6: merge GEMM + bias + residual ----------------
__global__ __launch_bounds__(256) void k_merge(
    const bf16* __restrict__ Wm_bf, const float* __restrict__ bm,
    const bf16* __restrict__ Rt, const float* __restrict__ x, float* __restrict__ out) {
  int blk = blockIdx.x;
  int b = blk / 320;
  int rem = blk - b * 320;
  int ct = rem >> 4, nb = rem & 15;
  int w = threadIdx.x >> 6, l = threadIdx.x & 63;
  int lg = l >> 4, lr = l & 15;
  int c0 = ct * 16, n0 = nb * 256 + w * 64;
  f32x4 acc[4] = {};
  const bf16* ap = Wm_bf + (c0 + lr) * 320 + 8 * lg;
  const bf16* bp = Rt + ((size_t)b * NN + n0 + lr) * 320 + 8 * lg;
#pragma unroll 2
  for (int f0 = 0; f0 < 320; f0 += 32) {
    bf16x8 a = *(const bf16x8*)(ap + f0);
#pragma unroll
    for (int j = 0; j < 4; j++) {
      bf16x8 bb = *(const bf16x8*)(bp + j * 16 * 320 + f0);
      acc[j] = mfma16(a, bb, acc[j]);
    }
  }
#pragma unroll
  for (int i = 0; i < 4; i++) {
    int c = c0 + 4 * lg + i;
    float bias = bm[c];
    const float* xp = x + ((size_t)b * 320 + c) * NN + n0 + lr;
    float* op = out + ((size_t)b * 320 + c) * NN + n0 + lr;
#pragma unroll
    for (int j = 0; j < 4; j++) op[j * 16] = acc[j][i] + bias + xp[j * 16];
  }
}

extern "C" void kernel_launch(void* const* d_in, const int* in_sizes, int n_in,
                              void* d_out, int out_size, void* d_ws, size_t ws_size,
                              hipStream_t stream) {
  const float* x  = (const float*)d_in[0];
  const float* Wq = (const float*)d_in[1];
  const float* bq = (const float*)d_in[2];
  const float* Wk = (const float*)d_in[3];
  const float* bk = (const float*)d_in[4];
  const float* Wv = (const float*)d_in[5];
  const float* bv = (const float*)d_in[6];
  const float* Wm = (const float*)d_in[7];
  const float* bm = (const float*)d_in[8];
  float* out = (float*)d_out;
  char* ws = (char*)d_ws;
  // workspace layout (bytes, 256-aligned)
  bf16*  W_all = (bf16*)(ws + 0);           //  448*320*2      = 286720
  bf16*  Wm_bf = (bf16*)(ws + 286720);      //  320*320*2      = 204800 -> 491520
  float* b_all = (float*)(ws + 491520);     //  448*4          -> pad 493568
  bf16*  xT    = (bf16*)(ws + 493568);      //  4*4096*320*2   = 10485760 -> 10979328
  float* QK    = (float*)(ws + 10979328);   //  4*128*4096*4   = 8388608  -> 19367936
  bf16*  Qn    = (bf16*)(ws + 19367936);    //  8*4096*32*2    = 2097152  -> 21465088
  bf16*  Kn    = (bf16*)(ws + 21465088);    //  2097152        -> 23562240
  bf16*  Vc    = (bf16*)(ws + 23562240);    //  8*128*5120*2   = 10485760 -> 34048000
  bf16*  Rt    = (bf16*)(ws + 34048000);    //  4*4096*320*2   = 10485760 -> 44533760

  k_prep<<<560, 256, 0, stream>>>(Wq, bq, Wk, bk, Wv, bv, Wm, W_all, Wm_bf, b_all);
  k_xt<<<2560, 256, 0, stream>>>(x, xT);
  k_proj<<<1792, 256, 0, stream>>>(W_all, b_all, xT, QK, Vc);
  k_norm<<<256, 256, 0, stream>>>(QK, Qn, Kn);
  k_attn<<<1024, 256, 0, stream>>>(Qn, Kn, Vc, Rt);
  k_merge<<<1280, 256, 0, stream>>>(Wm_bf, bm, Rt, x, out);
}